// Round 1
// 372.157 us; speedup vs baseline: 1.0031x; 1.0031x over previous
//
#include <hip/hip_runtime.h>
#include <cstdint>

#define B_ROWS 8192
#define KDIM 1024
#define N4 4096

typedef __attribute__((ext_vector_type(8))) short short8;
typedef __attribute__((ext_vector_type(4))) float float4v;

__device__ __forceinline__ unsigned short f2bf(float f) {
  union { float f; unsigned int u; } v; v.f = f;
  unsigned int r = v.u + 0x7fffu + ((v.u >> 16) & 1u);  // RNE
  return (unsigned short)(r >> 16);
}

__device__ __forceinline__ float bf2f(unsigned short s) {
  union { unsigned int u; float f; } v; v.u = ((unsigned int)s) << 16;
  return v.f;
}

__device__ __forceinline__ void async16(const unsigned short* g, unsigned short* l) {
  auto gp = (const __attribute__((address_space(1))) unsigned int*)(uintptr_t)g;
  auto lp = (__attribute__((address_space(3))) unsigned int*)(unsigned int)(uintptr_t)l;
  __builtin_amdgcn_global_load_lds(gp, lp, 16, 0, 0);
}

__device__ __forceinline__ float sigm(float v) { return 1.f / (1.f + expf(-v)); }

// ---------------- precast kernels ----------------

__global__ __launch_bounds__(256) void cast_bf16(const float* __restrict__ in0,
                                                 unsigned short* __restrict__ out0,
                                                 const float* __restrict__ in1,
                                                 unsigned short* __restrict__ out1) {
  const float* in = blockIdx.y ? in1 : in0;
  unsigned short* out = blockIdx.y ? out1 : out0;
  int i = (blockIdx.x * 256 + threadIdx.x) * 4;
  float4 v = *(const float4*)(in + i);
  ushort4 o;
  o.x = f2bf(v.x); o.y = f2bf(v.y); o.z = f2bf(v.z); o.w = f2bf(v.w);
  *(ushort4*)(out + i) = o;
}

__global__ __launch_bounds__(256) void transpose_cast(const float* __restrict__ W0,
                                                      unsigned short* __restrict__ Wt0,
                                                      const float* __restrict__ W1,
                                                      unsigned short* __restrict__ Wt1) {
  const float* W = blockIdx.z ? W1 : W0;
  unsigned short* Wt = blockIdx.z ? Wt1 : Wt0;
  __shared__ float tile[32][33];
  int n0 = blockIdx.x * 32;
  int k0 = blockIdx.y * 32;
  int tx = threadIdx.x & 31;
  int ty = threadIdx.x >> 5;
#pragma unroll
  for (int i = 0; i < 32; i += 8)
    tile[ty + i][tx] = W[(size_t)(k0 + ty + i) * N4 + n0 + tx];
  __syncthreads();
#pragma unroll
  for (int i = 0; i < 32; i += 8)
    Wt[(size_t)(n0 + ty + i) * KDIM + k0 + tx] = f2bf(tile[tx][ty + i]);
}

// ---------------- bf16 MFMA GEMM, 256x256 tile, BK=64, 8-wave 8-phase ----------------
// C[256][256] = A[256,K] * Wt[256,K]^T.  512 threads = 8 waves (2M x 4N),
// per-wave output 128x64 (acc[8][4] of f32x4).  LDS: 2 x (256x64) bf16 per
// operand, double buffered = 128 KiB.  Rotation swizzle (physical 16B slot c
// of row r holds logical k-chunk (c-r)&7); global_load_lds keeps a linear
// wave-uniform LDS dest and permutes the global source chunk per lane.
//
// Per K-tile: 4 phases x {ds_read subtile; 2 async stages of tile t+1;
// setprio(1); 16 MFMA; setprio(0); s_waitcnt vmcnt(4); s_barrier}.
// Stage deadline ledger (per wave, 2 loads/phase, in-order vmem completion):
//   issue t-P0: A-early (rows consumed at t+1-P0)  -> forced by end-t-P3 vmcnt(4)
//   issue t-P1: B-early (consumed t+1-P0)          -> forced by end-t-P3 vmcnt(4)
//   issue t-P2: B-late  (consumed t+1-P1)          -> forced by end-(t+1)-P0 vmcnt(4)
//   issue t-P3: A-late  (consumed t+1-P2)          -> forced by end-(t+1)-P1 vmcnt(4)
// so a uniform vmcnt(4) before every barrier is sufficient; never drains to 0.

__global__ __launch_bounds__(512, 2) void gemm_bf16(
    const unsigned short* __restrict__ Ah, const unsigned short* __restrict__ Wth,
    unsigned short* __restrict__ Uh,
    const unsigned short* __restrict__ Ax, const unsigned short* __restrict__ Wtx,
    unsigned short* __restrict__ Ux, int row0) {
  const unsigned short* A; const unsigned short* W; unsigned short* U;
  if (blockIdx.z == 0) { A = Ah; W = Wth; U = Uh; } else { A = Ax; W = Wtx; U = Ux; }

  __shared__ unsigned short ldsA[2 * 256 * 64];
  __shared__ unsigned short ldsB[2 * 256 * 64];

  const int tid = threadIdx.x;
  const int wave = tid >> 6;
  const int lane = tid & 63;
  const int wm2 = wave >> 2;  // 0..1 (M half)
  const int wn4 = wave & 3;   // 0..3 (N quarter)

  // bijective XCD swizzle (m204) over the x-y plane
  const int gx = N4 / 256;  // 16
  const int nwg = gx * (int)gridDim.y;
  const int f = (int)blockIdx.y * gx + (int)blockIdx.x;
  const int qq = nwg >> 3, rr = nwg & 7;
  const int xcd = f & 7, idx = f >> 3;
  const int wg = (xcd < rr) ? (xcd * (qq + 1) + idx)
                            : (rr * (qq + 1) + (xcd - rr) * qq + idx);
  const int bx = wg & (gx - 1);
  const int by = wg / gx;

  const int m0 = row0 + by * 256;
  const int n0 = bx * 256;

  // staging geometry: each wave-load covers 8 rows (64 lanes x 16B)
  const int r8 = lane >> 3;
  const int c8 = lane & 7;
  const int g8 = ((c8 - r8) & 7) * 8;  // element offset of logical chunk
  // per-wave 32-row regions, split by consumption deadline
  const int aE = (wave & 3) * 16 + (wave >> 2) * 128;  // A rows, deadline t+1-P0
  const int aL = aE + 64;                              // A rows, deadline t+1-P2
  const int bE = (wave >> 1) * 64 + (wave & 1) * 16;   // B rows, deadline t+1-P0
  const int bL = bE + 32;                              // B rows, deadline t+1-P1

  const unsigned short* gAe = A + (size_t)(m0 + aE + r8) * KDIM + g8;
  const unsigned short* gAl = A + (size_t)(m0 + aL + r8) * KDIM + g8;
  const unsigned short* gBe = W + (size_t)(n0 + bE + r8) * KDIM + g8;
  const unsigned short* gBl = W + (size_t)(n0 + bL + r8) * KDIM + g8;

  // fragment read offsets (elements). row = base + mi*16 + lq, chunk q = kk*4+lh,
  // physical slot = (q + row)&7 ; bases are multiples of 8 so slot = (q+lq)&7.
  const int lq = lane & 15, lh = lane >> 4;
  const int offA0 = (wm2 * 128 + lq) * 64 + ((lh + lq) & 7) * 8;
  const int offA1 = (wm2 * 128 + lq) * 64 + ((4 + lh + lq) & 7) * 8;
  const int offB0 = (wn4 * 64 + lq) * 64 + ((lh + lq) & 7) * 8;
  const int offB1 = (wn4 * 64 + lq) * 64 + ((4 + lh + lq) & 7) * 8;

  float4v acc[8][4];
  float4v zero = {0.f, 0.f, 0.f, 0.f};
#pragma unroll
  for (int i = 0; i < 8; ++i)
#pragma unroll
    for (int j = 0; j < 4; ++j) acc[i][j] = zero;

  // prologue: stage tile 0, deadline-ordered; require aE,bE done (allow bL,aL)
  async16(gAe, ldsA + aE * 64);
  async16(gAe + 8 * KDIM, ldsA + (aE + 8) * 64);
  async16(gBe, ldsB + bE * 64);
  async16(gBe + 8 * KDIM, ldsB + (bE + 8) * 64);
  async16(gBl, ldsB + bL * 64);
  async16(gBl + 8 * KDIM, ldsB + (bL + 8) * 64);
  async16(gAl, ldsA + aL * 64);
  async16(gAl + 8 * KDIM, ldsA + (aL + 8) * 64);
  asm volatile("s_waitcnt vmcnt(4)\n\ts_barrier" ::: "memory");

  short8 aF[4][2], bF[4][2];

#pragma unroll 2
  for (int t = 0; t < KDIM / 64; ++t) {
    const unsigned short* sA = ldsA + (t & 1) * 16384;
    const unsigned short* sB = ldsB + (t & 1) * 16384;
    unsigned short* dA = (unsigned short*)ldsA + ((t + 1) & 1) * 16384;
    unsigned short* dB = (unsigned short*)ldsB + ((t + 1) & 1) * 16384;
    const int k2 = (t + 1) * 64;  // ghost read at t=15 stays inside d_ws

    // ---- P0: read a[0..3], b[0,1]; stage A-early(t+1); MFMA Q0 ----
#pragma unroll
    for (int mi = 0; mi < 4; ++mi) {
      aF[mi][0] = *(const short8*)(sA + offA0 + mi * 1024);
      aF[mi][1] = *(const short8*)(sA + offA1 + mi * 1024);
    }
#pragma unroll
    for (int ni = 0; ni < 2; ++ni) {
      bF[ni][0] = *(const short8*)(sB + offB0 + ni * 1024);
      bF[ni][1] = *(const short8*)(sB + offB1 + ni * 1024);
    }
    async16(gAe + k2, dA + aE * 64);
    async16(gAe + k2 + 8 * KDIM, dA + (aE + 8) * 64);
    __builtin_amdgcn_s_setprio(1);
#pragma unroll
    for (int kk = 0; kk < 2; ++kk)
#pragma unroll
      for (int mi = 0; mi < 4; ++mi)
#pragma unroll
        for (int ni = 0; ni < 2; ++ni)
          acc[mi][ni] = __builtin_amdgcn_mfma_f32_16x16x32_bf16(aF[mi][kk], bF[ni][kk], acc[mi][ni], 0, 0, 0);
    __builtin_amdgcn_s_setprio(0);
    asm volatile("s_waitcnt vmcnt(4)\n\ts_barrier" ::: "memory");

    // ---- P1: read b[2,3]; stage B-early(t+1); MFMA Q1 ----
#pragma unroll
    for (int ni = 0; ni < 2; ++ni) {
      bF[2 + ni][0] = *(const short8*)(sB + offB0 + (2 + ni) * 1024);
      bF[2 + ni][1] = *(const short8*)(sB + offB1 + (2 + ni) * 1024);
    }
    async16(gBe + k2, dB + bE * 64);
    async16(gBe + k2 + 8 * KDIM, dB + (bE + 8) * 64);
    __builtin_amdgcn_s_setprio(1);
#pragma unroll
    for (int kk = 0; kk < 2; ++kk)
#pragma unroll
      for (int mi = 0; mi < 4; ++mi)
#pragma unroll
        for (int ni = 0; ni < 2; ++ni)
          acc[mi][2 + ni] = __builtin_amdgcn_mfma_f32_16x16x32_bf16(aF[mi][kk], bF[2 + ni][kk], acc[mi][2 + ni], 0, 0, 0);
    __builtin_amdgcn_s_setprio(0);
    asm volatile("s_waitcnt vmcnt(4)\n\ts_barrier" ::: "memory");

    // ---- P2: read a[4..7] (reuse aF); stage B-late(t+1); MFMA Q2 ----
#pragma unroll
    for (int mi = 0; mi < 4; ++mi) {
      aF[mi][0] = *(const short8*)(sA + offA0 + (4 + mi) * 1024);
      aF[mi][1] = *(const short8*)(sA + offA1 + (4 + mi) * 1024);
    }
    async16(gBl + k2, dB + bL * 64);
    async16(gBl + k2 + 8 * KDIM, dB + (bL + 8) * 64);
    __builtin_amdgcn_s_setprio(1);
#pragma unroll
    for (int kk = 0; kk < 2; ++kk)
#pragma unroll
      for (int mi = 0; mi < 4; ++mi)
#pragma unroll
        for (int ni = 0; ni < 2; ++ni)
          acc[4 + mi][ni] = __builtin_amdgcn_mfma_f32_16x16x32_bf16(aF[mi][kk], bF[ni][kk], acc[4 + mi][ni], 0, 0, 0);
    __builtin_amdgcn_s_setprio(0);
    asm volatile("s_waitcnt vmcnt(4)\n\ts_barrier" ::: "memory");

    // ---- P3: stage A-late(t+1); MFMA Q3 ----
    async16(gAl + k2, dA + aL * 64);
    async16(gAl + k2 + 8 * KDIM, dA + (aL + 8) * 64);
    __builtin_amdgcn_s_setprio(1);
#pragma unroll
    for (int kk = 0; kk < 2; ++kk)
#pragma unroll
      for (int mi = 0; mi < 4; ++mi)
#pragma unroll
        for (int ni = 0; ni < 2; ++ni)
          acc[4 + mi][2 + ni] = __builtin_amdgcn_mfma_f32_16x16x32_bf16(aF[mi][kk], bF[2 + ni][kk], acc[4 + mi][2 + ni], 0, 0, 0);
    __builtin_amdgcn_s_setprio(0);
    asm volatile("s_waitcnt vmcnt(4)\n\ts_barrier" ::: "memory");
  }
  asm volatile("s_waitcnt vmcnt(0)" ::: "memory");  // drain ghost stages before endpgm

  // epilogue: C/D layout col = lane&15, row = (lane>>4)*4 + reg; store bf16
  const int colc = lane & 15;
  const int rowq = (lane >> 4) * 4;
  unsigned short* Ub = U + (size_t)(by * 256 + wm2 * 128 + rowq) * N4 + n0 + wn4 * 64 + colc;
#pragma unroll
  for (int mi = 0; mi < 8; ++mi)
#pragma unroll
    for (int r = 0; r < 4; ++r) {
      unsigned short* Urow = Ub + (size_t)(mi * 16 + r) * N4;
#pragma unroll
      for (int ni = 0; ni < 4; ++ni) Urow[ni * 16] = f2bf(acc[mi][ni][r]);
    }
}

// ---------------- fused LN + LSTM pointwise (bf16 U) ----------------

__global__ __launch_bounds__(256) void fused_ln_lstm(
    const unsigned short* __restrict__ Uh, const unsigned short* __restrict__ Ux,
    const float* __restrict__ c0, const float* __restrict__ bias,
    const float* __restrict__ g1, const float* __restrict__ b1,
    const float* __restrict__ g2, const float* __restrict__ b2,
    const float* __restrict__ g3, const float* __restrict__ b3,
    float* __restrict__ h1o, float* __restrict__ c1o, int row0) {
  const int t = threadIdx.x;
  const int lane = t & 63;
  const int wv = t >> 6;
  const size_t rloc = blockIdx.x;
  const size_t rabs = rloc + (size_t)row0;

  const ushort4* uh = (const ushort4*)(Uh + rloc * N4);
  const ushort4* ux = (const ushort4*)(Ux + rloc * N4);
  float4 cold = ((const float4*)(c0 + rabs * KDIM))[t];  // issue early

  float4 vh[4], vx[4];
  float sh = 0.f, qh = 0.f, sx = 0.f, qx = 0.f;
#pragma unroll
  for (int k = 0; k < 4; ++k) {
    ushort4 au = uh[k * 256 + t];
    float4 a; a.x = bf2f(au.x); a.y = bf2f(au.y); a.z = bf2f(au.z); a.w = bf2f(au.w);
    vh[k] = a;
    sh += (a.x + a.y) + (a.z + a.w);
    qh += a.x * a.x + a.y * a.y + a.z * a.z + a.w * a.w;
    ushort4 bu = ux[k * 256 + t];
    float4 b; b.x = bf2f(bu.x); b.y = bf2f(bu.y); b.z = bf2f(bu.z); b.w = bf2f(bu.w);
    vx[k] = b;
    sx += (b.x + b.y) + (b.z + b.w);
    qx += b.x * b.x + b.y * b.y + b.z * b.z + b.w * b.w;
  }
  __shared__ float red[4][4];
#pragma unroll
  for (int o = 32; o > 0; o >>= 1) {
    sh += __shfl_down(sh, o); qh += __shfl_down(qh, o);
    sx += __shfl_down(sx, o); qx += __shfl_down(qx, o);
  }
  if (lane == 0) { red[wv][0] = sh; red[wv][1] = qh; red[wv][2] = sx; red[wv][3] = qx; }
  __syncthreads();
  sh = red[0][0] + red[1][0] + red[2][0] + red[3][0];
  qh = red[0][1] + red[1][1] + red[2][1] + red[3][1];
  sx = red[0][2] + red[1][2] + red[2][2] + red[3][2];
  qx = red[0][3] + red[1][3] + red[2][3] + red[3][3];
  const float inv4 = 1.f / 4096.f;
  const float muh = sh * inv4, mux = sx * inv4;
  const float rsh = rsqrtf(qh * inv4 - muh * muh + 1e-5f);
  const float rsx = rsqrtf(qx * inv4 - mux * mux + 1e-5f);

  float4 gate[4];
#pragma unroll
  for (int k = 0; k < 4; ++k) {
    int j = k * 256 + t;
    float4 G1 = ((const float4*)g1)[j], B1 = ((const float4*)b1)[j];
    float4 G2 = ((const float4*)g2)[j], B2 = ((const float4*)b2)[j];
    float4 BB = ((const float4*)bias)[j];
    float4 a = vh[k], b = vx[k], r;
    r.x = (a.x - muh) * rsh * G1.x + B1.x + (b.x - mux) * rsx * G2.x + B2.x + BB.x;
    r.y = (a.y - muh) * rsh * G1.y + B1.y + (b.y - mux) * rsx * G2.y + B2.y + BB.y;
    r.z = (a.z - muh) * rsh * G1.z + B1.z + (b.z - mux) * rsx * G2.z + B2.z + BB.z;
    r.w = (a.w - muh) * rsh * G1.w + B1.w + (b.w - mux) * rsx * G2.w + B2.w + BB.w;
    gate[k] = r;
  }
  float4 fg = gate[0], ig = gate[1], og = gate[2], cg = gate[3];
  float4 c1v;
  c1v.x = sigm(fg.x) * cold.x + sigm(ig.x) * tanhf(cg.x);
  c1v.y = sigm(fg.y) * cold.y + sigm(ig.y) * tanhf(cg.y);
  c1v.z = sigm(fg.z) * cold.z + sigm(ig.z) * tanhf(cg.z);
  c1v.w = sigm(fg.w) * cold.w + sigm(ig.w) * tanhf(cg.w);

  float sc = (c1v.x + c1v.y) + (c1v.z + c1v.w);
  float qc = c1v.x * c1v.x + c1v.y * c1v.y + c1v.z * c1v.z + c1v.w * c1v.w;
#pragma unroll
  for (int o = 32; o > 0; o >>= 1) { sc += __shfl_down(sc, o); qc += __shfl_down(qc, o); }
  __syncthreads();  // protect `red` reuse
  if (lane == 0) { red[wv][0] = sc; red[wv][1] = qc; }
  __syncthreads();
  sc = red[0][0] + red[1][0] + red[2][0] + red[3][0];
  qc = red[0][1] + red[1][1] + red[2][1] + red[3][1];
  const float invH = 1.f / 1024.f;
  const float muc = sc * invH;
  const float rsc = rsqrtf(qc * invH - muc * muc + 1e-5f);
  float4 G3 = ((const float4*)g3)[t], B3 = ((const float4*)b3)[t];
  float4 h1v;
  h1v.x = sigm(og.x) * tanhf((c1v.x - muc) * rsc * G3.x + B3.x);
  h1v.y = sigm(og.y) * tanhf((c1v.y - muc) * rsc * G3.y + B3.y);
  h1v.z = sigm(og.z) * tanhf((c1v.z - muc) * rsc * G3.z + B3.z);
  h1v.w = sigm(og.w) * tanhf((c1v.w - muc) * rsc * G3.w + B3.w);

  ((float4*)(h1o + rabs * KDIM))[t] = h1v;
  ((float4*)(c1o + rabs * KDIM))[t] = c1v;
}

// ---------------- launch ----------------

extern "C" void kernel_launch(void* const* d_in, const int* in_sizes, int n_in,
                              void* d_out, int out_size, void* d_ws, size_t ws_size,
                              hipStream_t stream) {
  const float* x    = (const float*)d_in[0];
  const float* h0   = (const float*)d_in[1];
  const float* c0   = (const float*)d_in[2];
  const float* Wh   = (const float*)d_in[3];
  const float* Wx   = (const float*)d_in[4];
  const float* bias = (const float*)d_in[5];
  const float* g1   = (const float*)d_in[6];
  const float* b1   = (const float*)d_in[7];
  const float* g2   = (const float*)d_in[8];
  const float* b2   = (const float*)d_in[9];
  const float* g3   = (const float*)d_in[10];
  const float* b3   = (const float*)d_in[11];
  float* h1o = (float*)d_out;
  float* c1o = h1o + (size_t)B_ROWS * KDIM;

  // ws layout: Ah bf16 | Ax bf16 | Wth bf16 | Wtx bf16 | U (chunked bf16 gate bufs)
  unsigned short* Ah  = (unsigned short*)d_ws;
  unsigned short* Ax  = Ah + (size_t)B_ROWS * KDIM;
  unsigned short* Wth = Ax + (size_t)B_ROWS * KDIM;
  unsigned short* Wtx = Wth + (size_t)N4 * KDIM;
  unsigned short* U = Wtx + (size_t)N4 * KDIM;
  size_t used = ((size_t)B_ROWS * KDIM * 2 + (size_t)N4 * KDIM * 2) * sizeof(unsigned short);
  size_t rem = ws_size > used ? ws_size - used : 0;
  int chunk = (int)(rem / ((size_t)2 * N4 * sizeof(unsigned short)));
  chunk &= ~255;
  if (chunk > B_ROWS) chunk = B_ROWS;
  if (chunk < 256) chunk = 256;  // assume ws_size is at least ~64MB

  cast_bf16<<<dim3(B_ROWS * KDIM / 1024, 2), 256, 0, stream>>>(h0, Ah, x, Ax);
  transpose_cast<<<dim3(N4 / 32, KDIM / 32, 2), 256, 0, stream>>>(Wh, Wth, Wx, Wtx);

  for (int r0 = 0; r0 < B_ROWS; r0 += chunk) {
    int rows = chunk;
    if (r0 + rows > B_ROWS) rows = B_ROWS - r0;
    unsigned short* Uh = U;
    unsigned short* Ux = U + (size_t)rows * N4;
    gemm_bf16<<<dim3(N4 / 256, rows / 256, 2), 512, 0, stream>>>(Ah, Wth, Uh, Ax, Wtx, Ux, r0);
    fused_ln_lstm<<<rows, 256, 0, stream>>>(Uh, Ux, c0, bias, g1, b1, g2, b2, g3, b3, h1o, c1o, r0);
  }
}

// Round 2
// 359.473 us; speedup vs baseline: 1.0385x; 1.0353x over previous
//
#include <hip/hip_runtime.h>
#include <cstdint>

#define B_ROWS 8192
#define KDIM 1024
#define N4 4096

typedef __attribute__((ext_vector_type(8))) short short8;
typedef __attribute__((ext_vector_type(4))) float float4v;

__device__ __forceinline__ unsigned short f2bf(float f) {
  union { float f; unsigned int u; } v; v.f = f;
  unsigned int r = v.u + 0x7fffu + ((v.u >> 16) & 1u);  // RNE
  return (unsigned short)(r >> 16);
}

__device__ __forceinline__ float bf2f(unsigned short s) {
  union { unsigned int u; float f; } v; v.u = ((unsigned int)s) << 16;
  return v.f;
}

__device__ __forceinline__ void async16(const unsigned short* g, unsigned short* l) {
  auto gp = (const __attribute__((address_space(1))) unsigned int*)(uintptr_t)g;
  auto lp = (__attribute__((address_space(3))) unsigned int*)(unsigned int)(uintptr_t)l;
  __builtin_amdgcn_global_load_lds(gp, lp, 16, 0, 0);
}

__device__ __forceinline__ float sigm(float v) { return 1.f / (1.f + expf(-v)); }

// ---------------- precast kernels ----------------

__global__ __launch_bounds__(256) void cast_bf16(const float* __restrict__ in0,
                                                 unsigned short* __restrict__ out0,
                                                 const float* __restrict__ in1,
                                                 unsigned short* __restrict__ out1) {
  const float* in = blockIdx.y ? in1 : in0;
  unsigned short* out = blockIdx.y ? out1 : out0;
  int i = (blockIdx.x * 256 + threadIdx.x) * 4;
  float4 v = *(const float4*)(in + i);
  ushort4 o;
  o.x = f2bf(v.x); o.y = f2bf(v.y); o.z = f2bf(v.z); o.w = f2bf(v.w);
  *(ushort4*)(out + i) = o;
}

__global__ __launch_bounds__(256) void transpose_cast(const float* __restrict__ W0,
                                                      unsigned short* __restrict__ Wt0,
                                                      const float* __restrict__ W1,
                                                      unsigned short* __restrict__ Wt1) {
  const float* W = blockIdx.z ? W1 : W0;
  unsigned short* Wt = blockIdx.z ? Wt1 : Wt0;
  __shared__ float tile[32][33];
  int n0 = blockIdx.x * 32;
  int k0 = blockIdx.y * 32;
  int tx = threadIdx.x & 31;
  int ty = threadIdx.x >> 5;
#pragma unroll
  for (int i = 0; i < 32; i += 8)
    tile[ty + i][tx] = W[(size_t)(k0 + ty + i) * N4 + n0 + tx];
  __syncthreads();
#pragma unroll
  for (int i = 0; i < 32; i += 8)
    Wt[(size_t)(n0 + ty + i) * KDIM + k0 + tx] = f2bf(tile[tx][ty + i]);
}

// ---------------- bf16 MFMA GEMM, 256x256 tile, BK=64, deep-pipelined ----------------
// C[256][256] = A[256,K] * Wt[256,K]^T.  512 threads = 8 waves (2M x 4N),
// per-wave output 128x64 (acc[8][4] of f32x4).  LDS: 2 x (256x64) bf16 per
// operand, double buffered = 128 KiB.  Rotation swizzle (physical 16B slot c
// of row r holds logical k-chunk (c-r)&7); global_load_lds keeps a linear
// wave-uniform LDS dest and permutes the global source chunk per lane.
//
// Deep-pipeline ledger (per wave; slice = 2 global_load_lds = 16 rows):
//   region read-completion within tile tau: AE@P0, BE@P0, BL@P1, AL@P23.
//   issue slots:  tau-P0:  AL(tau+1) -> other buf   (that region last read at tau-1)
//                 tau-P1:  AE(tau+2) -> current buf (read done at end-P0 + barrier)
//                 tau-P23: BE(tau+2), BL(tau+2) -> current buf
//   waits: uniform vmcnt(10) at end of P0, P1, P23 (3 per tile, never lower);
//   each wait forces exactly the slice(s) needed by the NEXT phase, issued
//   4-6 sub-phases (~1300 cyc) earlier -- load latency fully covered.
//   In-flight: 10-14 loads/wave in steady state.

__global__ __launch_bounds__(512, 2) void gemm_bf16(
    const unsigned short* __restrict__ Ah, const unsigned short* __restrict__ Wth,
    unsigned short* __restrict__ Uh,
    const unsigned short* __restrict__ Ax, const unsigned short* __restrict__ Wtx,
    unsigned short* __restrict__ Ux, int row0) {
  const unsigned short* A; const unsigned short* W; unsigned short* U;
  if (blockIdx.z == 0) { A = Ah; W = Wth; U = Uh; } else { A = Ax; W = Wtx; U = Ux; }

  __shared__ unsigned short ldsA[2 * 256 * 64];
  __shared__ unsigned short ldsB[2 * 256 * 64];

  const int tid = threadIdx.x;
  const int wave = tid >> 6;
  const int lane = tid & 63;
  const int wm2 = wave >> 2;  // 0..1 (M half)
  const int wn4 = wave & 3;   // 0..3 (N quarter)

  // bijective XCD swizzle (m204) over the x-y plane
  const int gx = N4 / 256;  // 16
  const int nwg = gx * (int)gridDim.y;
  const int f = (int)blockIdx.y * gx + (int)blockIdx.x;
  const int qq = nwg >> 3, rr = nwg & 7;
  const int xcd = f & 7, idx = f >> 3;
  const int wg = (xcd < rr) ? (xcd * (qq + 1) + idx)
                            : (rr * (qq + 1) + (xcd - rr) * qq + idx);
  const int bx = wg & (gx - 1);
  const int by = wg / gx;

  const int m0 = row0 + by * 256;
  const int n0 = bx * 256;

  // staging geometry: each wave-load covers 8 rows (64 lanes x 16B)
  const int r8 = lane >> 3;
  const int c8 = lane & 7;
  const int g8 = ((c8 - r8) & 7) * 8;  // element offset of logical chunk
  // per-wave 16-row slices, grouped by consumption phase
  const int aE = (wave & 3) * 16 + (wave >> 2) * 128;  // A rows, consumed P0
  const int aL = aE + 64;                              // A rows, consumed P23
  const int bE = (wave >> 1) * 64 + (wave & 1) * 16;   // B rows, consumed P0
  const int bL = bE + 32;                              // B rows, consumed P1

  const unsigned short* gAe = A + (size_t)(m0 + aE + r8) * KDIM + g8;
  const unsigned short* gAl = A + (size_t)(m0 + aL + r8) * KDIM + g8;
  const unsigned short* gBe = W + (size_t)(n0 + bE + r8) * KDIM + g8;
  const unsigned short* gBl = W + (size_t)(n0 + bL + r8) * KDIM + g8;

  // fragment read offsets (elements). row = base + mi*16 + lq, chunk q = kk*4+lh,
  // physical slot = (q + row)&7 ; bases are multiples of 8 so slot = (q+lq)&7.
  const int lq = lane & 15, lh = lane >> 4;
  const int offA0 = (wm2 * 128 + lq) * 64 + ((lh + lq) & 7) * 8;
  const int offA1 = (wm2 * 128 + lq) * 64 + ((4 + lh + lq) & 7) * 8;
  const int offB0 = (wn4 * 64 + lq) * 64 + ((lh + lq) & 7) * 8;
  const int offB1 = (wn4 * 64 + lq) * 64 + ((4 + lh + lq) & 7) * 8;

  float4v acc[8][4];
  float4v zero = {0.f, 0.f, 0.f, 0.f};
#pragma unroll
  for (int i = 0; i < 8; ++i)
#pragma unroll
    for (int j = 0; j < 4; ++j) acc[i][j] = zero;

#define STAGE2(gptr, lbase, kk)                                   \
  do {                                                            \
    async16((gptr) + (kk), (lbase));                              \
    async16((gptr) + (kk) + 8 * KDIM, (lbase) + 8 * 64);          \
  } while (0)

  // prologue: 7 slices in deadline order (AL(1) is issued by the loop at t=0-P0)
  STAGE2(gAe, ldsA + aE * 64, 0);
  STAGE2(gBe, ldsB + bE * 64, 0);
  STAGE2(gBl, ldsB + bL * 64, 0);
  STAGE2(gAl, ldsA + aL * 64, 0);
  STAGE2(gAe, ldsA + 16384 + aE * 64, 64);
  STAGE2(gBe, ldsB + 16384 + bE * 64, 64);
  STAGE2(gBl, ldsB + 16384 + bL * 64, 64);
  asm volatile("s_waitcnt vmcnt(10)\n\ts_barrier" ::: "memory");  // forces AE(0),BE(0)

  short8 aF[4][2], bF[4][2];

#pragma unroll 2
  for (int t = 0; t < KDIM / 64; ++t) {
    const unsigned short* sA = ldsA + (t & 1) * 16384;
    const unsigned short* sB = ldsB + (t & 1) * 16384;
    unsigned short* oA = (unsigned short*)ldsA + ((t + 1) & 1) * 16384;  // other buf
    unsigned short* cA = (unsigned short*)ldsA + (t & 1) * 16384;        // current buf
    unsigned short* cB = (unsigned short*)ldsB + (t & 1) * 16384;
    const int kAL = (t + 1) * 64;  // AL(t+1); ghost at t=15 stays in-bounds
    const int kNX = (t + 2) * 64;  // AE/BE/BL(t+2); ghosts stay in-bounds

    // ---- P0: read a[0..3], b[0,1]; stage AL(t+1)->other; MFMA Q0 ----
#pragma unroll
    for (int mi = 0; mi < 4; ++mi) {
      aF[mi][0] = *(const short8*)(sA + offA0 + mi * 1024);
      aF[mi][1] = *(const short8*)(sA + offA1 + mi * 1024);
    }
#pragma unroll
    for (int ni = 0; ni < 2; ++ni) {
      bF[ni][0] = *(const short8*)(sB + offB0 + ni * 1024);
      bF[ni][1] = *(const short8*)(sB + offB1 + ni * 1024);
    }
    STAGE2(gAl, oA + aL * 64, kAL);
    __builtin_amdgcn_s_setprio(1);
#pragma unroll
    for (int kk = 0; kk < 2; ++kk)
#pragma unroll
      for (int mi = 0; mi < 4; ++mi)
#pragma unroll
        for (int ni = 0; ni < 2; ++ni)
          acc[mi][ni] = __builtin_amdgcn_mfma_f32_16x16x32_bf16(aF[mi][kk], bF[ni][kk], acc[mi][ni], 0, 0, 0);
    __builtin_amdgcn_s_setprio(0);
    asm volatile("s_waitcnt vmcnt(10)\n\ts_barrier" ::: "memory");  // forces BL(t)

    // ---- P1: read b[2,3]; stage AE(t+2)->current; MFMA Q1 ----
#pragma unroll
    for (int ni = 0; ni < 2; ++ni) {
      bF[2 + ni][0] = *(const short8*)(sB + offB0 + (2 + ni) * 1024);
      bF[2 + ni][1] = *(const short8*)(sB + offB1 + (2 + ni) * 1024);
    }
    STAGE2(gAe, cA + aE * 64, kNX);
    __builtin_amdgcn_s_setprio(1);
#pragma unroll
    for (int kk = 0; kk < 2; ++kk)
#pragma unroll
      for (int mi = 0; mi < 4; ++mi)
#pragma unroll
        for (int ni = 0; ni < 2; ++ni)
          acc[mi][2 + ni] = __builtin_amdgcn_mfma_f32_16x16x32_bf16(aF[mi][kk], bF[2 + ni][kk], acc[mi][2 + ni], 0, 0, 0);
    __builtin_amdgcn_s_setprio(0);
    asm volatile("s_waitcnt vmcnt(10)\n\ts_barrier" ::: "memory");  // forces AL(t)

    // ---- P23: read a[4..7]; stage BE(t+2),BL(t+2)->current; MFMA Q2,Q3 ----
#pragma unroll
    for (int mi = 0; mi < 4; ++mi) {
      aF[mi][0] = *(const short8*)(sA + offA0 + (4 + mi) * 1024);
      aF[mi][1] = *(const short8*)(sA + offA1 + (4 + mi) * 1024);
    }
    STAGE2(gBe, cB + bE * 64, kNX);
    __builtin_amdgcn_s_setprio(1);
#pragma unroll
    for (int kk = 0; kk < 2; ++kk)
#pragma unroll
      for (int mi = 0; mi < 4; ++mi)
#pragma unroll
        for (int ni = 0; ni < 2; ++ni)
          acc[4 + mi][ni] = __builtin_amdgcn_mfma_f32_16x16x32_bf16(aF[mi][kk], bF[ni][kk], acc[4 + mi][ni], 0, 0, 0);
    __builtin_amdgcn_s_setprio(0);
    STAGE2(gBl, cB + bL * 64, kNX);
    __builtin_amdgcn_s_setprio(1);
#pragma unroll
    for (int kk = 0; kk < 2; ++kk)
#pragma unroll
      for (int mi = 0; mi < 4; ++mi)
#pragma unroll
        for (int ni = 0; ni < 2; ++ni)
          acc[4 + mi][2 + ni] = __builtin_amdgcn_mfma_f32_16x16x32_bf16(aF[mi][kk], bF[2 + ni][kk], acc[4 + mi][2 + ni], 0, 0, 0);
    __builtin_amdgcn_s_setprio(0);
    asm volatile("s_waitcnt vmcnt(10)\n\ts_barrier" ::: "memory");  // forces AE(t+1),BE(t+1)
  }
  asm volatile("s_waitcnt vmcnt(0)" ::: "memory");  // drain ghost stages before endpgm

  // epilogue: C/D layout col = lane&15, row = (lane>>4)*4 + reg; store bf16
  const int colc = lane & 15;
  const int rowq = (lane >> 4) * 4;
  unsigned short* Ub = U + (size_t)(by * 256 + wm2 * 128 + rowq) * N4 + n0 + wn4 * 64 + colc;
#pragma unroll
  for (int mi = 0; mi < 8; ++mi)
#pragma unroll
    for (int r = 0; r < 4; ++r) {
      unsigned short* Urow = Ub + (size_t)(mi * 16 + r) * N4;
#pragma unroll
      for (int ni = 0; ni < 4; ++ni) Urow[ni * 16] = f2bf(acc[mi][ni][r]);
    }
}

// ---------------- fused LN + LSTM pointwise (bf16 U) ----------------

__global__ __launch_bounds__(256) void fused_ln_lstm(
    const unsigned short* __restrict__ Uh, const unsigned short* __restrict__ Ux,
    const float* __restrict__ c0, const float* __restrict__ bias,
    const float* __restrict__ g1, const float* __restrict__ b1,
    const float* __restrict__ g2, const float* __restrict__ b2,
    const float* __restrict__ g3, const float* __restrict__ b3,
    float* __restrict__ h1o, float* __restrict__ c1o, int row0) {
  const int t = threadIdx.x;
  const int lane = t & 63;
  const int wv = t >> 6;
  const size_t rloc = blockIdx.x;
  const size_t rabs = rloc + (size_t)row0;

  const ushort4* uh = (const ushort4*)(Uh + rloc * N4);
  const ushort4* ux = (const ushort4*)(Ux + rloc * N4);
  float4 cold = ((const float4*)(c0 + rabs * KDIM))[t];  // issue early

  float4 vh[4], vx[4];
  float sh = 0.f, qh = 0.f, sx = 0.f, qx = 0.f;
#pragma unroll
  for (int k = 0; k < 4; ++k) {
    ushort4 au = uh[k * 256 + t];
    float4 a; a.x = bf2f(au.x); a.y = bf2f(au.y); a.z = bf2f(au.z); a.w = bf2f(au.w);
    vh[k] = a;
    sh += (a.x + a.y) + (a.z + a.w);
    qh += a.x * a.x + a.y * a.y + a.z * a.z + a.w * a.w;
    ushort4 bu = ux[k * 256 + t];
    float4 b; b.x = bf2f(bu.x); b.y = bf2f(bu.y); b.z = bf2f(bu.z); b.w = bf2f(bu.w);
    vx[k] = b;
    sx += (b.x + b.y) + (b.z + b.w);
    qx += b.x * b.x + b.y * b.y + b.z * b.z + b.w * b.w;
  }
  __shared__ float red[4][4];
#pragma unroll
  for (int o = 32; o > 0; o >>= 1) {
    sh += __shfl_down(sh, o); qh += __shfl_down(qh, o);
    sx += __shfl_down(sx, o); qx += __shfl_down(qx, o);
  }
  if (lane == 0) { red[wv][0] = sh; red[wv][1] = qh; red[wv][2] = sx; red[wv][3] = qx; }
  __syncthreads();
  sh = red[0][0] + red[1][0] + red[2][0] + red[3][0];
  qh = red[0][1] + red[1][1] + red[2][1] + red[3][1];
  sx = red[0][2] + red[1][2] + red[2][2] + red[3][2];
  qx = red[0][3] + red[1][3] + red[2][3] + red[3][3];
  const float inv4 = 1.f / 4096.f;
  const float muh = sh * inv4, mux = sx * inv4;
  const float rsh = rsqrtf(qh * inv4 - muh * muh + 1e-5f);
  const float rsx = rsqrtf(qx * inv4 - mux * mux + 1e-5f);

  float4 gate[4];
#pragma unroll
  for (int k = 0; k < 4; ++k) {
    int j = k * 256 + t;
    float4 G1 = ((const float4*)g1)[j], B1 = ((const float4*)b1)[j];
    float4 G2 = ((const float4*)g2)[j], B2 = ((const float4*)b2)[j];
    float4 BB = ((const float4*)bias)[j];
    float4 a = vh[k], b = vx[k], r;
    r.x = (a.x - muh) * rsh * G1.x + B1.x + (b.x - mux) * rsx * G2.x + B2.x + BB.x;
    r.y = (a.y - muh) * rsh * G1.y + B1.y + (b.y - mux) * rsx * G2.y + B2.y + BB.y;
    r.z = (a.z - muh) * rsh * G1.z + B1.z + (b.z - mux) * rsx * G2.z + B2.z + BB.z;
    r.w = (a.w - muh) * rsh * G1.w + B1.w + (b.w - mux) * rsx * G2.w + B2.w + BB.w;
    gate[k] = r;
  }
  float4 fg = gate[0], ig = gate[1], og = gate[2], cg = gate[3];
  float4 c1v;
  c1v.x = sigm(fg.x) * cold.x + sigm(ig.x) * tanhf(cg.x);
  c1v.y = sigm(fg.y) * cold.y + sigm(ig.y) * tanhf(cg.y);
  c1v.z = sigm(fg.z) * cold.z + sigm(ig.z) * tanhf(cg.z);
  c1v.w = sigm(fg.w) * cold.w + sigm(ig.w) * tanhf(cg.w);

  float sc = (c1v.x + c1v.y) + (c1v.z + c1v.w);
  float qc = c1v.x * c1v.x + c1v.y * c1v.y + c1v.z * c1v.z + c1v.w * c1v.w;
#pragma unroll
  for (int o = 32; o > 0; o >>= 1) { sc += __shfl_down(sc, o); qc += __shfl_down(qc, o); }
  __syncthreads();  // protect `red` reuse
  if (lane == 0) { red[wv][0] = sc; red[wv][1] = qc; }
  __syncthreads();
  sc = red[0][0] + red[1][0] + red[2][0] + red[3][0];
  qc = red[0][1] + red[1][1] + red[2][1] + red[3][1];
  const float invH = 1.f / 1024.f;
  const float muc = sc * invH;
  const float rsc = rsqrtf(qc * invH - muc * muc + 1e-5f);
  float4 G3 = ((const float4*)g3)[t], B3 = ((const float4*)b3)[t];
  float4 h1v;
  h1v.x = sigm(og.x) * tanhf((c1v.x - muc) * rsc * G3.x + B3.x);
  h1v.y = sigm(og.y) * tanhf((c1v.y - muc) * rsc * G3.y + B3.y);
  h1v.z = sigm(og.z) * tanhf((c1v.z - muc) * rsc * G3.z + B3.z);
  h1v.w = sigm(og.w) * tanhf((c1v.w - muc) * rsc * G3.w + B3.w);

  ((float4*)(h1o + rabs * KDIM))[t] = h1v;
  ((float4*)(c1o + rabs * KDIM))[t] = c1v;
}

// ---------------- launch ----------------

extern "C" void kernel_launch(void* const* d_in, const int* in_sizes, int n_in,
                              void* d_out, int out_size, void* d_ws, size_t ws_size,
                              hipStream_t stream) {
  const float* x    = (const float*)d_in[0];
  const float* h0   = (const float*)d_in[1];
  const float* c0   = (const float*)d_in[2];
  const float* Wh   = (const float*)d_in[3];
  const float* Wx   = (const float*)d_in[4];
  const float* bias = (const float*)d_in[5];
  const float* g1   = (const float*)d_in[6];
  const float* b1   = (const float*)d_in[7];
  const float* g2   = (const float*)d_in[8];
  const float* b2   = (const float*)d_in[9];
  const float* g3   = (const float*)d_in[10];
  const float* b3   = (const float*)d_in[11];
  float* h1o = (float*)d_out;
  float* c1o = h1o + (size_t)B_ROWS * KDIM;

  // ws layout: Ah bf16 | Ax bf16 | Wth bf16 | Wtx bf16 | U (chunked bf16 gate bufs)
  unsigned short* Ah  = (unsigned short*)d_ws;
  unsigned short* Ax  = Ah + (size_t)B_ROWS * KDIM;
  unsigned short* Wth = Ax + (size_t)B_ROWS * KDIM;
  unsigned short* Wtx = Wth + (size_t)N4 * KDIM;
  unsigned short* U = Wtx + (size_t)N4 * KDIM;
  size_t used = ((size_t)B_ROWS * KDIM * 2 + (size_t)N4 * KDIM * 2) * sizeof(unsigned short);
  size_t rem = ws_size > used ? ws_size - used : 0;
  int chunk = (int)(rem / ((size_t)2 * N4 * sizeof(unsigned short)));
  chunk &= ~255;
  if (chunk > B_ROWS) chunk = B_ROWS;
  if (chunk < 256) chunk = 256;  // assume ws_size is at least ~64MB

  cast_bf16<<<dim3(B_ROWS * KDIM / 1024, 2), 256, 0, stream>>>(h0, Ah, x, Ax);
  transpose_cast<<<dim3(N4 / 32, KDIM / 32, 2), 256, 0, stream>>>(Wh, Wth, Wx, Wtx);

  for (int r0 = 0; r0 < B_ROWS; r0 += chunk) {
    int rows = chunk;
    if (r0 + rows > B_ROWS) rows = B_ROWS - r0;
    unsigned short* Uh = U;
    unsigned short* Ux = U + (size_t)rows * N4;
    gemm_bf16<<<dim3(N4 / 256, rows / 256, 2), 512, 0, stream>>>(Ah, Wth, Uh, Ax, Wtx, Ux, r0);
    fused_ln_lstm<<<rows, 256, 0, stream>>>(Uh, Ux, c0, bias, g1, b1, g2, b2, g3, b3, h1o, c1o, r0);
  }
}